// Round 1
// baseline (1109.556 us; speedup 1.0000x reference)
//
#include <hip/hip_runtime.h>
#include <hip/hip_bf16.h>

#define S 2048
#define D 1024
#define H 16
#define DK 64

// ---------------------------------------------------------------------------
// Projection GEMM: Y = X @ W^T + b
//   X: (S x D) row-major, W: (D x D) row-major (torch Linear), b: (D)
// LAYOUT 0: scatter into heads (H, S, DK):  Y[(n>>6)*S*DK + m*DK + (n&63)]
// LAYOUT 1: plain row-major (S x D):        Y[m*D + n]
// 64x64 tile per block, 256 threads, 4x4 accum per thread, K-tiles of 16.
// ---------------------------------------------------------------------------
template <int LAYOUT>
__global__ __launch_bounds__(256) void proj_kernel(
    const float* __restrict__ X, const float* __restrict__ W,
    const float* __restrict__ b, float* __restrict__ Y) {
  __shared__ float Xs[64][17];
  __shared__ float Ws[64][17];
  const int tx = threadIdx.x & 15;
  const int ty = threadIdx.x >> 4;
  const int m0 = blockIdx.y * 64;
  const int n0 = blockIdx.x * 64;

  const int lr = threadIdx.x >> 2;         // 0..63 : row within tile
  const int lc = (threadIdx.x & 3) << 2;   // 0,4,8,12 : col within k-tile

  float c[4][4] = {};

  for (int k0 = 0; k0 < D; k0 += 16) {
    float4 xv = *(const float4*)&X[(size_t)(m0 + lr) * D + k0 + lc];
    float4 wv = *(const float4*)&W[(size_t)(n0 + lr) * D + k0 + lc];
    Xs[lr][lc + 0] = xv.x; Xs[lr][lc + 1] = xv.y;
    Xs[lr][lc + 2] = xv.z; Xs[lr][lc + 3] = xv.w;
    Ws[lr][lc + 0] = wv.x; Ws[lr][lc + 1] = wv.y;
    Ws[lr][lc + 2] = wv.z; Ws[lr][lc + 3] = wv.w;
    __syncthreads();
#pragma unroll
    for (int kk = 0; kk < 16; ++kk) {
      float xr[4], wr[4];
#pragma unroll
      for (int i = 0; i < 4; ++i) xr[i] = Xs[ty + 16 * i][kk];
#pragma unroll
      for (int j = 0; j < 4; ++j) wr[j] = Ws[tx + 16 * j][kk];
#pragma unroll
      for (int i = 0; i < 4; ++i)
#pragma unroll
        for (int j = 0; j < 4; ++j) c[i][j] += xr[i] * wr[j];
    }
    __syncthreads();
  }

#pragma unroll
  for (int i = 0; i < 4; ++i) {
#pragma unroll
    for (int j = 0; j < 4; ++j) {
      const int m = m0 + ty + 16 * i;
      const int n = n0 + tx + 16 * j;
      const float val = c[i][j] + b[n];
      if (LAYOUT == 0) {
        Y[(size_t)(n >> 6) * (S * DK) + (size_t)m * DK + (n & 63)] = val;
      } else {
        Y[(size_t)m * D + n] = val;
      }
    }
  }
}

// ---------------------------------------------------------------------------
// Scores: Sc[h][q][k] = dot(Qh[h][q][:], Kh[h][k][:]) / 8, masked.
// One block computes a 64x64 tile for one head; full K=64 staged in LDS.
// ---------------------------------------------------------------------------
__global__ __launch_bounds__(256) void scores_kernel(
    const float* __restrict__ Qh, const float* __restrict__ Kh,
    const int* __restrict__ mask, float* __restrict__ Sc) {
  __shared__ float Qs[64][65];
  __shared__ float Ks[64][65];
  const int h = blockIdx.z;
  const int q0 = blockIdx.y * 64;
  const int k0 = blockIdx.x * 64;
  const float* Q = Qh + (size_t)h * S * DK;
  const float* K = Kh + (size_t)h * S * DK;

  // Load 64x64 tiles: 1024 float4s, 256 threads x 4 float4.
#pragma unroll
  for (int ii = 0; ii < 4; ++ii) {
    const int f = threadIdx.x + 256 * ii;
    const int r = f >> 4;
    const int c = (f & 15) << 2;
    float4 qv = *(const float4*)&Q[(size_t)(q0 + r) * DK + c];
    float4 kv = *(const float4*)&K[(size_t)(k0 + r) * DK + c];
    Qs[r][c + 0] = qv.x; Qs[r][c + 1] = qv.y;
    Qs[r][c + 2] = qv.z; Qs[r][c + 3] = qv.w;
    Ks[r][c + 0] = kv.x; Ks[r][c + 1] = kv.y;
    Ks[r][c + 2] = kv.z; Ks[r][c + 3] = kv.w;
  }
  __syncthreads();

  const int tx = threadIdx.x & 15;
  const int ty = threadIdx.x >> 4;
  float c[4][4] = {};
#pragma unroll 8
  for (int kk = 0; kk < 64; ++kk) {
    float qr[4], kr[4];
#pragma unroll
    for (int i = 0; i < 4; ++i) qr[i] = Qs[ty + 16 * i][kk];
#pragma unroll
    for (int j = 0; j < 4; ++j) kr[j] = Ks[tx + 16 * j][kk];
#pragma unroll
    for (int i = 0; i < 4; ++i)
#pragma unroll
      for (int j = 0; j < 4; ++j) c[i][j] += qr[i] * kr[j];
  }

#pragma unroll
  for (int j = 0; j < 4; ++j) {
    const int kI = k0 + tx + 16 * j;
    const int mj = mask[kI];
#pragma unroll
    for (int i = 0; i < 4; ++i) {
      const int qI = q0 + ty + 16 * i;
      float val = c[i][j] * 0.125f;
      if (mj == 0) val = -1e9f;
      Sc[(size_t)h * S * S + (size_t)qI * S + kI] = val;
    }
  }
}

// ---------------------------------------------------------------------------
// Row softmax, in place. One block (256 threads) per (h,q) row of 2048.
// ---------------------------------------------------------------------------
__global__ __launch_bounds__(256) void softmax_kernel(float* __restrict__ P) {
  const size_t row = blockIdx.x;
  float* p = P + row * (size_t)S;
  const int t = threadIdx.x;
  const int wave = t >> 6;
  const int lane = t & 63;

  float4 a0 = ((const float4*)p)[t];
  float4 a1 = ((const float4*)p)[t + 256];

  float m = fmaxf(fmaxf(fmaxf(a0.x, a0.y), fmaxf(a0.z, a0.w)),
                  fmaxf(fmaxf(a1.x, a1.y), fmaxf(a1.z, a1.w)));
#pragma unroll
  for (int off = 32; off >= 1; off >>= 1) m = fmaxf(m, __shfl_xor(m, off, 64));

  __shared__ float wm[4];
  __shared__ float wsum[4];
  if (lane == 0) wm[wave] = m;
  __syncthreads();
  m = fmaxf(fmaxf(wm[0], wm[1]), fmaxf(wm[2], wm[3]));

  float e[8];
  e[0] = __expf(a0.x - m); e[1] = __expf(a0.y - m);
  e[2] = __expf(a0.z - m); e[3] = __expf(a0.w - m);
  e[4] = __expf(a1.x - m); e[5] = __expf(a1.y - m);
  e[6] = __expf(a1.z - m); e[7] = __expf(a1.w - m);

  float s = e[0] + e[1] + e[2] + e[3] + e[4] + e[5] + e[6] + e[7];
#pragma unroll
  for (int off = 32; off >= 1; off >>= 1) s += __shfl_xor(s, off, 64);
  if (lane == 0) wsum[wave] = s;
  __syncthreads();
  const float total = wsum[0] + wsum[1] + wsum[2] + wsum[3];
  const float inv = 1.0f / total;

  a0.x = e[0] * inv; a0.y = e[1] * inv; a0.z = e[2] * inv; a0.w = e[3] * inv;
  a1.x = e[4] * inv; a1.y = e[5] * inv; a1.z = e[6] * inv; a1.w = e[7] * inv;
  ((float4*)p)[t] = a0;
  ((float4*)p)[t + 256] = a1;
}

// ---------------------------------------------------------------------------
// ctx[h][q][dk] -> stored as ctx[q*D + h*DK + dk] = sum_k P[h][q][k]*Vh[h][k][dk]
// Block: 64 q-rows x full DK=64 for one head. K-tiles of 16.
// ---------------------------------------------------------------------------
__global__ __launch_bounds__(256) void ctx_kernel(
    const float* __restrict__ P, const float* __restrict__ Vh,
    float* __restrict__ ctx) {
  __shared__ float Ps[64][17];
  __shared__ float Vs[16][65];
  const int h = blockIdx.y;
  const int q0 = blockIdx.x * 64;
  const float* Pp = P + (size_t)h * S * S;
  const float* Vp = Vh + (size_t)h * S * DK;

  const int tx = threadIdx.x & 15;
  const int ty = threadIdx.x >> 4;
  float c[4][4] = {};

  for (int k0 = 0; k0 < S; k0 += 16) {
    {  // P tile 64x16
      const int r = threadIdx.x >> 2;
      const int cc = (threadIdx.x & 3) << 2;
      float4 pv = *(const float4*)&Pp[(size_t)(q0 + r) * S + k0 + cc];
      Ps[r][cc + 0] = pv.x; Ps[r][cc + 1] = pv.y;
      Ps[r][cc + 2] = pv.z; Ps[r][cc + 3] = pv.w;
    }
    {  // V tile 16x64
      const int r = threadIdx.x >> 4;
      const int cc = (threadIdx.x & 15) << 2;
      float4 vv = *(const float4*)&Vp[(size_t)(k0 + r) * DK + cc];
      Vs[r][cc + 0] = vv.x; Vs[r][cc + 1] = vv.y;
      Vs[r][cc + 2] = vv.z; Vs[r][cc + 3] = vv.w;
    }
    __syncthreads();
#pragma unroll
    for (int kk = 0; kk < 16; ++kk) {
      float pr[4], vr[4];
#pragma unroll
      for (int i = 0; i < 4; ++i) pr[i] = Ps[ty + 16 * i][kk];
#pragma unroll
      for (int j = 0; j < 4; ++j) vr[j] = Vs[kk][tx + 16 * j];
#pragma unroll
      for (int i = 0; i < 4; ++i)
#pragma unroll
        for (int j = 0; j < 4; ++j) c[i][j] += pr[i] * vr[j];
    }
    __syncthreads();
  }

#pragma unroll
  for (int i = 0; i < 4; ++i)
#pragma unroll
    for (int j = 0; j < 4; ++j) {
      const int q = q0 + ty + 16 * i;
      const int dk = tx + 16 * j;
      ctx[(size_t)q * D + h * DK + dk] = c[i][j];
    }
}

extern "C" void kernel_launch(void* const* d_in, const int* in_sizes, int n_in,
                              void* d_out, int out_size, void* d_ws,
                              size_t ws_size, hipStream_t stream) {
  const float* q = (const float*)d_in[0];
  const float* k = (const float*)d_in[1];
  const float* v = (const float*)d_in[2];
  const int* mask = (const int*)d_in[3];
  const float* Wq = (const float*)d_in[4];
  const float* bq = (const float*)d_in[5];
  const float* Wk = (const float*)d_in[6];
  const float* bk = (const float*)d_in[7];
  const float* Wv = (const float*)d_in[8];
  const float* bv = (const float*)d_in[9];
  const float* Wo = (const float*)d_in[10];
  const float* bo = (const float*)d_in[11];

  float* out = (float*)d_out;                    // (S, D)
  float* attn = out + (size_t)S * D;             // (H, S, S)

  float* Qh = (float*)d_ws;                      // (H, S, DK)
  float* Kh = Qh + (size_t)S * D;
  float* Vh = Kh + (size_t)S * D;
  float* ctx = Vh + (size_t)S * D;               // (S, D)

  dim3 pgrid(D / 64, S / 64);                    // (16, 32)
  proj_kernel<0><<<pgrid, 256, 0, stream>>>(q, Wq, bq, Qh);
  proj_kernel<0><<<pgrid, 256, 0, stream>>>(k, Wk, bk, Kh);
  proj_kernel<0><<<pgrid, 256, 0, stream>>>(v, Wv, bv, Vh);

  dim3 sgrid(S / 64, S / 64, H);                 // (32, 32, 16)
  scores_kernel<<<sgrid, 256, 0, stream>>>(Qh, Kh, mask, attn);

  softmax_kernel<<<dim3(H * S), 256, 0, stream>>>(attn);

  ctx_kernel<<<dim3(S / 64, H), 256, 0, stream>>>(attn, Vh, ctx);

  proj_kernel<1><<<pgrid, 256, 0, stream>>>(ctx, Wo, bo, out);
}

// Round 2
// 545.145 us; speedup vs baseline: 2.0353x; 2.0353x over previous
//
#include <hip/hip_runtime.h>
#include <hip/hip_bf16.h>

#define S 2048
#define D 1024
#define H 16
#define DK 64

typedef __bf16 bf16x8 __attribute__((ext_vector_type(8)));
typedef __bf16 bf16x4 __attribute__((ext_vector_type(4)));
typedef float f32x4 __attribute__((ext_vector_type(4)));

#define LDT 72  // LDS tile row stride in bf16 elems (pad: 144B rows -> 2-way max)

#define MFMA(a, b, c) __builtin_amdgcn_mfma_f32_16x16x32_bf16((a), (b), (c), 0, 0, 0)

// ---------------------------------------------------------------------------
// Projection GEMM via MFMA: Y = X @ W^T + b.  X:(S x D) XT in {float,__bf16},
// W:(D x D) fp32 row-major (torch Linear), b:(D).
// LAYOUT 0: Q/K heads, bf16 [h][s][dk]
// LAYOUT 1: plain fp32 [s][d]  (final output)
// LAYOUT 2: V head-transposed, bf16 [h][dk][s]
// Block: 64x64 tile, 4 waves in 2x2, each wave 32x32 (2x2 MFMA frags).
// ---------------------------------------------------------------------------
template <typename XT, int LAYOUT>
__global__ __launch_bounds__(256) void proj_mfma(
    const XT* __restrict__ X, const float* __restrict__ W,
    const float* __restrict__ bias, void* __restrict__ Yv) {
  __shared__ __bf16 Xs[64 * LDT];
  __shared__ __bf16 Ws[64 * LDT];
  const int t = threadIdx.x;
  const int lane = t & 63, wid = t >> 6;
  const int m0 = blockIdx.y * 64, n0 = blockIdx.x * 64;
  const int srow = t >> 2, scol = (t & 3) * 16;
  const int wm = (wid >> 1) * 32, wn = (wid & 1) * 32;
  const int fm = lane & 15, fk = (lane >> 4) * 8, r0 = (lane >> 4) * 4;

  f32x4 acc[2][2] = {};

  for (int k0 = 0; k0 < D; k0 += 64) {
    // stage X tile (64x64), convert to bf16 if needed
    if constexpr (sizeof(XT) == 4) {
      const float* src = (const float*)X + (size_t)(m0 + srow) * D + k0 + scol;
      bf16x8 v0, v1;
#pragma unroll
      for (int i = 0; i < 8; i += 4) {
        float4 f = *(const float4*)(src + i);
        v0[i + 0] = (__bf16)f.x; v0[i + 1] = (__bf16)f.y;
        v0[i + 2] = (__bf16)f.z; v0[i + 3] = (__bf16)f.w;
      }
#pragma unroll
      for (int i = 0; i < 8; i += 4) {
        float4 f = *(const float4*)(src + 8 + i);
        v1[i + 0] = (__bf16)f.x; v1[i + 1] = (__bf16)f.y;
        v1[i + 2] = (__bf16)f.z; v1[i + 3] = (__bf16)f.w;
      }
      *(bf16x8*)&Xs[srow * LDT + scol] = v0;
      *(bf16x8*)&Xs[srow * LDT + scol + 8] = v1;
    } else {
      const __bf16* src = (const __bf16*)X + (size_t)(m0 + srow) * D + k0 + scol;
      *(bf16x8*)&Xs[srow * LDT + scol] = *(const bf16x8*)src;
      *(bf16x8*)&Xs[srow * LDT + scol + 8] = *(const bf16x8*)(src + 8);
    }
    {
      const float* src = W + (size_t)(n0 + srow) * D + k0 + scol;
      bf16x8 v0, v1;
#pragma unroll
      for (int i = 0; i < 8; i += 4) {
        float4 f = *(const float4*)(src + i);
        v0[i + 0] = (__bf16)f.x; v0[i + 1] = (__bf16)f.y;
        v0[i + 2] = (__bf16)f.z; v0[i + 3] = (__bf16)f.w;
      }
#pragma unroll
      for (int i = 0; i < 8; i += 4) {
        float4 f = *(const float4*)(src + 8 + i);
        v1[i + 0] = (__bf16)f.x; v1[i + 1] = (__bf16)f.y;
        v1[i + 2] = (__bf16)f.z; v1[i + 3] = (__bf16)f.w;
      }
      *(bf16x8*)&Ws[srow * LDT + scol] = v0;
      *(bf16x8*)&Ws[srow * LDT + scol + 8] = v1;
    }
    __syncthreads();
#pragma unroll
    for (int ks = 0; ks < 2; ++ks) {
      const int kb = ks * 32 + fk;
      bf16x8 a0 = *(const bf16x8*)&Xs[(wm + fm) * LDT + kb];
      bf16x8 a1 = *(const bf16x8*)&Xs[(wm + 16 + fm) * LDT + kb];
      bf16x8 b0 = *(const bf16x8*)&Ws[(wn + fm) * LDT + kb];
      bf16x8 b1 = *(const bf16x8*)&Ws[(wn + 16 + fm) * LDT + kb];
      acc[0][0] = MFMA(a0, b0, acc[0][0]);
      acc[0][1] = MFMA(a0, b1, acc[0][1]);
      acc[1][0] = MFMA(a1, b0, acc[1][0]);
      acc[1][1] = MFMA(a1, b1, acc[1][1]);
    }
    __syncthreads();
  }

#pragma unroll
  for (int mi = 0; mi < 2; ++mi) {
#pragma unroll
    for (int ni = 0; ni < 2; ++ni) {
      const int n = n0 + wn + ni * 16 + fm;
      const float bn = bias[n];
      if constexpr (LAYOUT == 2) {
        const int mrow = m0 + wm + mi * 16 + r0;
        bf16x4 pk;
#pragma unroll
        for (int r = 0; r < 4; ++r) pk[r] = (__bf16)(acc[mi][ni][r] + bn);
        __bf16* Y = (__bf16*)Yv;
        *(bf16x4*)&Y[(size_t)(n >> 6) * DK * S + (size_t)(n & 63) * S + mrow] = pk;
      } else {
#pragma unroll
        for (int r = 0; r < 4; ++r) {
          const int m = m0 + wm + mi * 16 + r0 + r;
          const float val = acc[mi][ni][r] + bn;
          if constexpr (LAYOUT == 0) {
            ((__bf16*)Yv)[(size_t)(n >> 6) * S * DK + (size_t)m * DK + (n & 63)] =
                (__bf16)val;
          } else {
            ((float*)Yv)[(size_t)m * D + n] = val;
          }
        }
      }
    }
  }
}

// ---------------------------------------------------------------------------
// Pass A: online softmax stats (row max m, row sum-exp l) per (h,q).
// One block per (q-tile of 64, head). Wave w owns q rows [w*16, w*16+16).
// ---------------------------------------------------------------------------
__global__ __launch_bounds__(256) void attn_stats(
    const __bf16* __restrict__ Qh, const __bf16* __restrict__ Kh,
    const int* __restrict__ mask, float2* __restrict__ stats) {
  __shared__ __bf16 Qs[64 * LDT];
  __shared__ __bf16 Ks[64 * LDT];
  const int t = threadIdx.x, lane = t & 63, wid = t >> 6;
  const int h = blockIdx.y, q0 = blockIdx.x * 64;
  const int srow = t >> 2, scol = (t & 3) * 16;
  const int fm = lane & 15, fk = (lane >> 4) * 8, r0 = (lane >> 4) * 4;
  const __bf16* Qg = Qh + (size_t)h * S * DK;
  const __bf16* Kg = Kh + (size_t)h * S * DK;

  {
    const __bf16* src = Qg + (size_t)(q0 + srow) * DK + scol;
    *(bf16x8*)&Qs[srow * LDT + scol] = *(const bf16x8*)src;
    *(bf16x8*)&Qs[srow * LDT + scol + 8] = *(const bf16x8*)(src + 8);
  }

  float m_run[4], l_run[4];
#pragma unroll
  for (int r = 0; r < 4; ++r) { m_run[r] = -1e30f; l_run[r] = 0.f; }

  for (int k0 = 0; k0 < S; k0 += 64) {
    __syncthreads();
    {
      const __bf16* src = Kg + (size_t)(k0 + srow) * DK + scol;
      *(bf16x8*)&Ks[srow * LDT + scol] = *(const bf16x8*)src;
      *(bf16x8*)&Ks[srow * LDT + scol + 8] = *(const bf16x8*)(src + 8);
    }
    __syncthreads();
    f32x4 acc[4] = {};
#pragma unroll
    for (int ks = 0; ks < 2; ++ks) {
      const int kb = ks * 32 + fk;
      bf16x8 a = *(const bf16x8*)&Qs[(wid * 16 + fm) * LDT + kb];
#pragma unroll
      for (int nt = 0; nt < 4; ++nt) {
        bf16x8 bb = *(const bf16x8*)&Ks[(nt * 16 + fm) * LDT + kb];
        acc[nt] = MFMA(a, bb, acc[nt]);
      }
    }
    int mk[4];
#pragma unroll
    for (int nt = 0; nt < 4; ++nt) mk[nt] = mask[k0 + nt * 16 + fm];
#pragma unroll
    for (int r = 0; r < 4; ++r) {
      float s[4];
      float mt = -1e30f;
#pragma unroll
      for (int nt = 0; nt < 4; ++nt) {
        s[nt] = mk[nt] ? acc[nt][r] * 0.125f : -1e9f;
        mt = fmaxf(mt, s[nt]);
      }
      mt = fmaxf(mt, __shfl_xor(mt, 1, 64));
      mt = fmaxf(mt, __shfl_xor(mt, 2, 64));
      mt = fmaxf(mt, __shfl_xor(mt, 4, 64));
      mt = fmaxf(mt, __shfl_xor(mt, 8, 64));
      const float mnew = fmaxf(m_run[r], mt);
      float ps = __expf(s[0] - mnew) + __expf(s[1] - mnew) +
                 __expf(s[2] - mnew) + __expf(s[3] - mnew);
      ps += __shfl_xor(ps, 1, 64);
      ps += __shfl_xor(ps, 2, 64);
      ps += __shfl_xor(ps, 4, 64);
      ps += __shfl_xor(ps, 8, 64);
      l_run[r] = l_run[r] * __expf(m_run[r] - mnew) + ps;
      m_run[r] = mnew;
    }
  }
  if (fm == 0) {
#pragma unroll
    for (int r = 0; r < 4; ++r) {
      const int q = q0 + wid * 16 + r0 + r;
      stats[h * S + q] = make_float2(m_run[r], l_run[r]);
    }
  }
}

// ---------------------------------------------------------------------------
// Pass B: recompute scores, normalize with stats, write attn (fp32, the
// required output) once, and accumulate ctx = P @ V via LDS round-trip
// (P leaves QK^T in C-layout, re-enters PV in A-layout).
// ctx written bf16 [s][d] for the final projection.
// ---------------------------------------------------------------------------
__global__ __launch_bounds__(256) void attn_ctx(
    const __bf16* __restrict__ Qh, const __bf16* __restrict__ Kh,
    const __bf16* __restrict__ Vt, const int* __restrict__ mask,
    const float2* __restrict__ stats, float* __restrict__ attn,
    __bf16* __restrict__ ctx) {
  __shared__ __bf16 Qs[64 * LDT];
  __shared__ __bf16 Ks[64 * LDT];
  __shared__ __bf16 Vs[64 * LDT];
  __shared__ __bf16 Ps[64 * LDT];
  const int t = threadIdx.x, lane = t & 63, wid = t >> 6;
  const int h = blockIdx.y, q0 = blockIdx.x * 64;
  const int srow = t >> 2, scol = (t & 3) * 16;
  const int fm = lane & 15, fk = (lane >> 4) * 8, r0 = (lane >> 4) * 4;
  const __bf16* Qg = Qh + (size_t)h * S * DK;
  const __bf16* Kg = Kh + (size_t)h * S * DK;
  const __bf16* Vg = Vt + (size_t)h * DK * S;
  float* attnH = attn + (size_t)h * S * S;

  {
    const __bf16* src = Qg + (size_t)(q0 + srow) * DK + scol;
    *(bf16x8*)&Qs[srow * LDT + scol] = *(const bf16x8*)src;
    *(bf16x8*)&Qs[srow * LDT + scol + 8] = *(const bf16x8*)(src + 8);
  }
  float mrow[4], invl[4];
#pragma unroll
  for (int r = 0; r < 4; ++r) {
    float2 st = stats[h * S + q0 + wid * 16 + r0 + r];
    mrow[r] = st.x;
    invl[r] = 1.0f / st.y;
  }

  f32x4 cacc[4] = {};

  for (int k0 = 0; k0 < S; k0 += 64) {
    __syncthreads();
    {
      const __bf16* src = Kg + (size_t)(k0 + srow) * DK + scol;
      *(bf16x8*)&Ks[srow * LDT + scol] = *(const bf16x8*)src;
      *(bf16x8*)&Ks[srow * LDT + scol + 8] = *(const bf16x8*)(src + 8);
      const __bf16* vsrc = Vg + (size_t)srow * S + k0 + scol;
      *(bf16x8*)&Vs[srow * LDT + scol] = *(const bf16x8*)vsrc;
      *(bf16x8*)&Vs[srow * LDT + scol + 8] = *(const bf16x8*)(vsrc + 8);
    }
    __syncthreads();
    f32x4 acc[4] = {};
#pragma unroll
    for (int ks = 0; ks < 2; ++ks) {
      const int kb = ks * 32 + fk;
      bf16x8 a = *(const bf16x8*)&Qs[(wid * 16 + fm) * LDT + kb];
#pragma unroll
      for (int nt = 0; nt < 4; ++nt) {
        bf16x8 bb = *(const bf16x8*)&Ks[(nt * 16 + fm) * LDT + kb];
        acc[nt] = MFMA(a, bb, acc[nt]);
      }
    }
#pragma unroll
    for (int nt = 0; nt < 4; ++nt) {
      const int mk = mask[k0 + nt * 16 + fm];
#pragma unroll
      for (int r = 0; r < 4; ++r) {
        const float sv = mk ? acc[nt][r] * 0.125f : -1e9f;
        const float p = __expf(sv - mrow[r]) * invl[r];
        const int qrow = wid * 16 + r0 + r;
        attnH[(size_t)(q0 + qrow) * S + k0 + nt * 16 + fm] = p;
        Ps[qrow * LDT + nt * 16 + fm] = (__bf16)p;
      }
    }
    __syncthreads();
#pragma unroll
    for (int ks = 0; ks < 2; ++ks) {
      const int kb = ks * 32 + fk;
      bf16x8 a = *(const bf16x8*)&Ps[(wid * 16 + fm) * LDT + kb];
#pragma unroll
      for (int nt = 0; nt < 4; ++nt) {
        bf16x8 bb = *(const bf16x8*)&Vs[(nt * 16 + fm) * LDT + kb];
        cacc[nt] = MFMA(a, bb, cacc[nt]);
      }
    }
  }

#pragma unroll
  for (int nt = 0; nt < 4; ++nt) {
#pragma unroll
    for (int r = 0; r < 4; ++r) {
      const int q = q0 + wid * 16 + r0 + r;
      const int dk = nt * 16 + fm;
      ctx[(size_t)q * D + h * DK + dk] = (__bf16)cacc[nt][r];
    }
  }
}

extern "C" void kernel_launch(void* const* d_in, const int* in_sizes, int n_in,
                              void* d_out, int out_size, void* d_ws,
                              size_t ws_size, hipStream_t stream) {
  const float* q = (const float*)d_in[0];
  const float* k = (const float*)d_in[1];
  const float* v = (const float*)d_in[2];
  const int* mask = (const int*)d_in[3];
  const float* Wq = (const float*)d_in[4];
  const float* bq = (const float*)d_in[5];
  const float* Wk = (const float*)d_in[6];
  const float* bk = (const float*)d_in[7];
  const float* Wv = (const float*)d_in[8];
  const float* bv = (const float*)d_in[9];
  const float* Wo = (const float*)d_in[10];
  const float* bo = (const float*)d_in[11];

  float* out = (float*)d_out;          // (S, D) fp32
  float* attn = out + (size_t)S * D;   // (H, S, S) fp32

  __bf16* Qh = (__bf16*)d_ws;                  // (H,S,DK) bf16
  __bf16* Kh = Qh + (size_t)S * D;             // (H,S,DK) bf16
  __bf16* Vt = Kh + (size_t)S * D;             // (H,DK,S) bf16
  __bf16* ctxb = Vt + (size_t)S * D;           // (S,D)    bf16
  float2* stats = (float2*)(ctxb + (size_t)S * D);  // (H*S) {m,l}

  dim3 pgrid(D / 64, S / 64);  // (16,32)
  proj_mfma<float, 0><<<pgrid, 256, 0, stream>>>(q, Wq, bq, Qh);
  proj_mfma<float, 0><<<pgrid, 256, 0, stream>>>(k, Wk, bk, Kh);
  proj_mfma<float, 2><<<pgrid, 256, 0, stream>>>(v, Wv, bv, Vt);

  dim3 agrid(S / 64, H);  // (32,16)
  attn_stats<<<agrid, 256, 0, stream>>>(Qh, Kh, mask, stats);
  attn_ctx<<<agrid, 256, 0, stream>>>(Qh, Kh, Vt, mask, stats, attn, ctxb);

  proj_mfma<__bf16, 1><<<pgrid, 256, 0, stream>>>(ctxb, Wo, bo, out);
}